// Round 14
// baseline (5999.380 us; speedup 1.0000x reference)
//
#include <hip/hip_runtime.h>
#include <hip/hip_bf16.h>
#include <stdint.h>

// SubLSTM T=1024, B=64, H=512, GATE=3H, L=2 — round 14: LAYER-SPLIT swarms.
// Insight: only each layer's SELF-recurrence is latency-critical; the L0->L1
// edge is feed-forward and pipelines. So: 512 blocks (2/CU guaranteed by
// __launch_bounds__(256,2)): blocks 0-255 = L0 swarm, 256-511 = L1 swarm,
// running CONCURRENTLY. Each swarm: 8 groups x 32 blocks (16 h-cols each).
//
// L0 round t: check peers' h0_{t-1} (ring0) -> B1 -> stash x_{t+1}; wave3
//   back-pressure check -> a0b = hA@R0 (a0a_sav precomputed) -> proj -> B2 ->
//   publish h0_t (ring0 slot t&7, depth 8) -> a0a_next = x_{t+1}@W0 ->
//   issue x_{t+2} + next sweep.
// L1 round t: flush prev out -> check h0_t feed (always ready: L1 lags) +
//   peers' h1_{t-1} (ring1 depth 4) -> prog := t+1 -> B1 -> a1a=hF@W1 +
//   a1b=hB@R1 -> proj -> B2 -> publish h1_t + pend out -> issue next sweeps.
// Back-pressure: L0 may reuse ring0 slot t&7 (destroying h0_{t-8}) only when
// all 32 L1 group blocks have prog >= t-7. Dependency chain strictly
// decreases -> deadlock-free; budget bail everywhere.
// Protocol: u64 = (tag32<<32)|(2xbf16) relaxed agent atomics (data IS flag).
// Replay-safe: prog memset 0 per call; stale ring tags either mismatch (spin)
// or are bit-identical deterministic payloads; 0xAA never matches a tag.

#define TSTEPS 1024
#define BATCH  64
#define HID    512
#define GATE   1536
#define GROWS  8
#define NT     256

typedef unsigned long long u64;
typedef __attribute__((ext_vector_type(8))) short short8;
typedef __attribute__((ext_vector_type(4))) short short4v;
typedef __attribute__((ext_vector_type(4))) float floatx4;

__device__ __forceinline__ float sigmoidf_(float x) { return 1.0f / (1.0f + __expf(-x)); }

__device__ __forceinline__ unsigned short f2bf(float x) {
    union { float f; unsigned u; } v; v.f = x;
    unsigned r = v.u + 0x7FFFu + ((v.u >> 16) & 1u);   // RNE
    return (unsigned short)(r >> 16);
}

__device__ __forceinline__ short8 load_frag(const float* p) {
    floatx4 a = *(const floatx4*)p;
    floatx4 b = *(const floatx4*)(p + 4);
    short8 r;
#pragma unroll
    for (int j = 0; j < 4; ++j) { r[j] = (short)f2bf(a[j]); r[j+4] = (short)f2bf(b[j]); }
    return r;
}

__device__ __forceinline__ u64 ring_ld(const u64* p) {
    return __hip_atomic_load(p, __ATOMIC_RELAXED, __HIP_MEMORY_SCOPE_AGENT);
}
__device__ __forceinline__ void ring_st(u64* p, u64 v) {
    __hip_atomic_store(p, v, __ATOMIC_RELAXED, __HIP_MEMORY_SCOPE_AGENT);
}
__device__ __forceinline__ unsigned prog_ld(const unsigned* p) {
    return __hip_atomic_load(p, __ATOMIC_RELAXED, __HIP_MEMORY_SCOPE_AGENT);
}
__device__ __forceinline__ void prog_st(unsigned* p, unsigned v) {
    __hip_atomic_store(p, v, __ATOMIC_RELAXED, __HIP_MEMORY_SCOPE_AGENT);
}

// ---- preamble: x f32 -> bf16 ----
__global__ __launch_bounds__(256) void xconvert(const float* __restrict__ x,
                                                unsigned short* __restrict__ xb) {
    const size_t i = ((size_t)blockIdx.x*256 + threadIdx.x) * 8;
    floatx4 a = *(const floatx4*)(x + i);
    floatx4 b = *(const floatx4*)(x + i + 4);
    short8 p;
#pragma unroll
    for (int j = 0; j < 4; ++j) { p[j] = (short)f2bf(a[j]); p[j+4] = (short)f2bf(b[j]); }
    *(short8*)(xb + i) = p;
}

__global__ __launch_bounds__(NT, 2) void sublstm_split(
    const unsigned short* __restrict__ xb,
    const float* __restrict__ W,
    const float* __restrict__ R,
    const float* __restrict__ bi,
    const float* __restrict__ bh,
    const float* __restrict__ fw,
    const float* __restrict__ h0,
    const float* __restrict__ c0,
    u64* __restrict__ ring0,       // [slot 8][grp 8][blk 32][row 8][unit 8]
    u64* __restrict__ ring1,       // [slot 4][grp 8][blk 32][row 8][unit 8]
    unsigned* __restrict__ prog,   // [grp 8][blk 32] x 16B stride
    float* __restrict__ out)
{
    const int tid  = threadIdx.x;
    const int lane = tid & 63;
    const int wid  = tid >> 6;            // 0,1,2 = i/o/z gate waves; 3 = helper
    const int bid  = blockIdx.x;
    const bool isL0 = (bid < 256);
    const int b    = isL0 ? bid : (bid - 256);
    const int g    = b & 7;               // batch group (XCD-affine heuristic)
    const int bidx = b >> 3;              // 0..31: 16-col slice
    const int col0 = bidx << 4;

    __shared__ __align__(16) unsigned short tA[16][520];  // L0: x tile | L1: h0 feed
    __shared__ __align__(16) unsigned short tB[16][520];  // L0: hA     | L1: hB
    __shared__ float proj[3][16][17];

    for (int i = tid; i < 16*520; i += NT) {
        ((unsigned short*)tA)[i] = 0;
        ((unsigned short*)tB)[i] = 0;
    }
    __syncthreads();

    const int lrow = lane & 15;
    const int lk   = (lane >> 4) << 3;

    // ---- weights: this block's layer only (gate waves) ----
    short8 wa[16], wb[16];               // L0: W0,R0 | L1: W1,R1
    float bias = 0.f;
    if (wid < 3) {
        const size_t lo = isL0 ? 0 : (size_t)GATE;
        const int wrow = wid*HID + col0 + lrow;
#pragma unroll
        for (int kc = 0; kc < 16; ++kc) {
            wa[kc] = load_frag(W + (lo + wrow)*HID + kc*32 + lk);
            wb[kc] = load_frag(R + (lo + wrow)*HID + kc*32 + lk);
        }
        bias = bi[lo + wrow] + bh[lo + wrow];
    }

    // ---- state: 128 cells on waves 0,1 ----
    const bool active = (tid < 128);
    const int srow = (tid >> 4) & 7;
    const int scol = tid & 15;
    const int lyr  = isL0 ? 0 : 1;
    const float fgv = sigmoidf_(fw[(size_t)lyr*HID + col0 + scol]);
    float creg = active ? c0[((size_t)lyr*BATCH + g*GROWS + srow)*HID + col0 + scol] : 0.f;

    // ---- prologue staging ----
    if (isL0) {
        const unsigned short* xp = xb + (size_t)g*GROWS*HID;
        for (int w = tid; w < GROWS*HID/8; w += NT) {
            const int r = w >> 6, c8 = (w & 63) << 3;
            *(short8*)(&tA[r][c8]) = *(const short8*)(xp + (size_t)r*HID + c8);
        }
        const float* hp = h0 + (size_t)g*GROWS*HID;           // layer-0 h init
        for (int w = tid; w < GROWS*HID/4; w += NT) {
            const int r = w >> 7, c4 = (w & 127) << 2;
            floatx4 v = *(const floatx4*)(hp + (size_t)r*HID + c4);
            short4v p4;
#pragma unroll
            for (int j = 0; j < 4; ++j) p4[j] = (short)f2bf(v[j]);
            *(short4v*)(&tB[r][c4]) = p4;
        }
    } else {
        const float* hp = h0 + ((size_t)BATCH + g*GROWS)*HID; // layer-1 h init
        for (int w = tid; w < GROWS*HID/4; w += NT) {
            const int r = w >> 7, c4 = (w & 127) << 2;
            floatx4 v = *(const floatx4*)(hp + (size_t)r*HID + c4);
            short4v p4;
#pragma unroll
            for (int j = 0; j < 4; ++j) p4[j] = (short)f2bf(v[j]);
            *(short4v*)(&tB[r][c4]) = p4;
        }
    }
    __syncthreads();

    floatx4 a0a_sav = {0,0,0,0};
    short8 xr0, xr1;
    u64 va[16];
    if (isL0) {
        if (wid < 3) {   // a0a for t=0: x_0 @ W0
#pragma unroll
            for (int kc = 0; kc < 16; ++kc) {
                short8 afx = *(const short8*)(&tA[lrow][kc*32 + lk]);
                a0a_sav = __builtin_amdgcn_mfma_f32_16x16x32_bf16(afx, wa[kc], a0a_sav, 0, 0, 0);
            }
        }
        const unsigned short* xp = xb + (size_t)BATCH*HID + (size_t)g*GROWS*HID;  // x_1
        xr0 = *(const short8*)(xp + (size_t)(tid >> 6)*HID + ((tid & 63) << 3));
        const int w1 = tid + 256;
        xr1 = *(const short8*)(xp + (size_t)(w1 >> 6)*HID + ((w1 & 63) << 3));
    } else {
        // issue vh sweep for h0_0 (ring0 slot 0, tag 1)
        const u64* rb = ring0 + (size_t)g*2048;
#pragma unroll
        for (int k = 0; k < 8; ++k) va[k] = ring_ld(rb + tid + (k << 8));
    }

    int budget = 1 << 22;
    int pend_t = -1;
    float pend_h = 0.f, pend_c = 0.f;

    for (int t = 0; t < TSTEPS; ++t) {
        if (isL0) {
            // ==== A: check peers' h0_{t-1} -> tB ====
            if (t >= 1) {
                const unsigned want = (unsigned)t;
                const u64* rb = ring0 + ((size_t)((t - 1) & 7)*8 + g)*2048;
                unsigned stale = 0;
#pragma unroll
                for (int k = 0; k < 8; ++k)
                    if ((unsigned)(va[k] >> 32) != want) stale |= (1u << k);
                int pass = 0;
                while (__any((int)(stale != 0)) && budget > 0) {
                    if (pass++) __builtin_amdgcn_s_sleep(1);
#pragma unroll
                    for (int k = 0; k < 8; ++k)
                        if (stale & (1u << k)) va[k] = ring_ld(rb + tid + (k << 8));
#pragma unroll
                    for (int k = 0; k < 8; ++k)
                        if (stale & (1u << k))
                            if ((unsigned)(va[k] >> 32) == want) stale &= ~(1u << k);
                    --budget;
                }
#pragma unroll
                for (int k = 0; k < 8; ++k) {
                    const int w = tid + (k << 8);
                    const int bb = w >> 6, r = (w >> 3) & 7, u = w & 7;
                    *(unsigned*)(&tB[r][bb*16 + u*2]) = (unsigned)va[k];
                }
            }
            __syncthreads();   // B1

            // stash x_{t+1} (xr loaded a round ago); back-pressure on wave 3
            if (t + 1 < TSTEPS) {
                *(short8*)(&tA[tid >> 6][(tid & 63) << 3]) = xr0;
                const int w1 = tid + 256;
                *(short8*)(&tA[w1 >> 6][(w1 & 63) << 3]) = xr1;
            }
            if (wid == 3 && t >= 8) {
                const unsigned* pp = prog + (size_t)g*32*4;
                while (budget > 0) {
                    unsigned v = 0xFFFFFFFFu;
                    if (lane < 32) v = prog_ld(pp + (size_t)lane*4);
                    if (__all((int)((lane >= 32) || ((int)v >= t - 7)))) break;
                    __builtin_amdgcn_s_sleep(1);
                    --budget;
                }
            }
            floatx4 ae = {0,0,0,0}, ao = {0,0,0,0};
            if (wid < 3) {   // a0b = hA @ R0, 2 chains
#pragma unroll
                for (int kc = 0; kc < 16; kc += 2) {
                    short8 h0f = *(const short8*)(&tB[lrow][kc*32 + lk]);
                    short8 h1f = *(const short8*)(&tB[lrow][(kc+1)*32 + lk]);
                    ae = __builtin_amdgcn_mfma_f32_16x16x32_bf16(h0f, wb[kc],   ae, 0, 0, 0);
                    ao = __builtin_amdgcn_mfma_f32_16x16x32_bf16(h1f, wb[kc+1], ao, 0, 0, 0);
                }
                const int erow0 = (lane >> 4) << 2, ecol = lrow;
#pragma unroll
                for (int q = 0; q < 4; ++q)
                    proj[wid][erow0 + q][ecol] = sigmoidf_(a0a_sav[q] + ae[q] + ao[q] + bias);
            }
            __syncthreads();   // B2

            // ==== E: state update + publish h0_t ====
            if (active) {
                const float ig = proj[0][srow][scol];
                const float og = proj[1][srow][scol];
                const float zz = proj[2][srow][scol];
                const float c_ = creg*fgv + zz - ig;
                creg = c_;
                const float h_ = sigmoidf_(c_) - og;
                const unsigned hu = __float_as_uint(h_);
                const unsigned pu = (unsigned)__builtin_amdgcn_ds_swizzle((int)hu, 0x041F);
                unsigned pay;
                asm volatile("v_cvt_pk_bf16_f32 %0, %1, %2"
                             : "=v"(pay) : "v"(h_), "v"(__uint_as_float(pu)));
                if (!(scol & 1)) {
                    const size_t off = (((size_t)(t & 7)*8 + g)*32 + bidx)*64
                                     + srow*8 + (scol >> 1);
                    ring_st(ring0 + off, (u64)pay | ((u64)(unsigned)(t + 1) << 32));
                }
                if (t == TSTEPS - 1) {                    // L0 finals
                    const size_t fo = (size_t)TSTEPS*BATCH*HID
                                    + ((size_t)g*GROWS + srow)*HID + col0 + scol;
                    out[fo] = h_;
                    out[fo + (size_t)2*BATCH*HID] = c_;
                }
            }
            // a0a_next = x_{t+1} @ W0 (off the publish->check path of peers)
            if (wid < 3 && t + 1 < TSTEPS) {
                floatx4 an = {0,0,0,0};
#pragma unroll
                for (int kc = 0; kc < 16; ++kc) {
                    short8 afx = *(const short8*)(&tA[lrow][kc*32 + lk]);
                    an = __builtin_amdgcn_mfma_f32_16x16x32_bf16(afx, wa[kc], an, 0, 0, 0);
                }
                a0a_sav = an;
            }
            // issues: x_{t+2}; next sweep (h0_t, slot t&7)
            if (t + 2 < TSTEPS) {
                const unsigned short* xp = xb + ((size_t)(t + 2)*BATCH + g*GROWS)*HID;
                xr0 = *(const short8*)(xp + (size_t)(tid >> 6)*HID + ((tid & 63) << 3));
                const int w1 = tid + 256;
                xr1 = *(const short8*)(xp + (size_t)(w1 >> 6)*HID + ((w1 & 63) << 3));
            }
            if (t + 1 < TSTEPS) {
                const u64* rb = ring0 + ((size_t)(t & 7)*8 + g)*2048;
#pragma unroll
                for (int k = 0; k < 8; ++k) va[k] = ring_ld(rb + tid + (k << 8));
            }
        } else {
            // ==== L1 ====
            // flush prev round's out stores (oldest vmem this round)
            if (pend_t >= 0) {
                out[((size_t)pend_t*BATCH + g*GROWS + srow)*HID + col0 + scol] = pend_h;
                pend_t = -1;
            }
            // A: check h0_t feed (k<8, tag t+1) + peers' h1_{t-1} (k>=8, tag t)
            {
                const unsigned wantF = (unsigned)(t + 1);
                const unsigned wantB = (unsigned)t;
                const int kmax = (t >= 1) ? 16 : 8;
                const u64* rbF = ring0 + ((size_t)(t & 7)*8 + g)*2048;
                const u64* rbB = ring1 + ((size_t)((t - 1) & 3)*8 + g)*2048;
                unsigned stale = 0;
#pragma unroll
                for (int k = 0; k < 16; ++k)
                    if (k < kmax)
                        if ((unsigned)(va[k] >> 32) != ((k < 8) ? wantF : wantB))
                            stale |= (1u << k);
                int pass = 0;
                while (__any((int)(stale != 0)) && budget > 0) {
                    if (pass++) __builtin_amdgcn_s_sleep(1);
#pragma unroll
                    for (int k = 0; k < 16; ++k)
                        if (k < kmax && (stale & (1u << k)))
                            va[k] = ring_ld((k < 8) ? (rbF + tid + (k << 8))
                                                    : (rbB + tid + ((k - 8) << 8)));
#pragma unroll
                    for (int k = 0; k < 16; ++k)
                        if (k < kmax && (stale & (1u << k)))
                            if ((unsigned)(va[k] >> 32) == ((k < 8) ? wantF : wantB))
                                stale &= ~(1u << k);
                    --budget;
                }
#pragma unroll
                for (int k = 0; k < 16; ++k) {
                    if (k < kmax) {
                        const int w = tid + ((k & 7) << 8);
                        const int bb = w >> 6, r = (w >> 3) & 7, u = w & 7;
                        unsigned* dst = (k < 8)
                            ? (unsigned*)(&tA[r][bb*16 + u*2])
                            : (unsigned*)(&tB[r][bb*16 + u*2]);
                        *dst = (unsigned)va[k];
                    }
                }
                if (tid == 0)   // consumed h0_t -> release L0 slot t-? for reuse
                    prog_st(prog + ((size_t)g*32 + bidx)*4, (unsigned)(t + 1));
            }
            __syncthreads();   // B1

            floatx4 fe = {0,0,0,0}, fo_ = {0,0,0,0}, be = {0,0,0,0}, bo = {0,0,0,0};
            if (wid < 3) {   // a1a = hF@W1 + a1b = hB@R1, 4 chains
#pragma unroll
                for (int kc = 0; kc < 16; kc += 2) {
                    short8 f0 = *(const short8*)(&tA[lrow][kc*32 + lk]);
                    short8 f1 = *(const short8*)(&tA[lrow][(kc+1)*32 + lk]);
                    short8 b0 = *(const short8*)(&tB[lrow][kc*32 + lk]);
                    short8 b1 = *(const short8*)(&tB[lrow][(kc+1)*32 + lk]);
                    fe  = __builtin_amdgcn_mfma_f32_16x16x32_bf16(f0, wa[kc],   fe,  0, 0, 0);
                    fo_ = __builtin_amdgcn_mfma_f32_16x16x32_bf16(f1, wa[kc+1], fo_, 0, 0, 0);
                    be  = __builtin_amdgcn_mfma_f32_16x16x32_bf16(b0, wb[kc],   be,  0, 0, 0);
                    bo  = __builtin_amdgcn_mfma_f32_16x16x32_bf16(b1, wb[kc+1], bo,  0, 0, 0);
                }
                const int erow0 = (lane >> 4) << 2, ecol = lrow;
#pragma unroll
                for (int q = 0; q < 4; ++q)
                    proj[wid][erow0 + q][ecol] =
                        sigmoidf_(fe[q] + fo_[q] + be[q] + bo[q] + bias);
            }
            __syncthreads();   // B2

            // ==== E: state update + publish h1_t; defer out store ====
            if (active) {
                const float ig = proj[0][srow][scol];
                const float og = proj[1][srow][scol];
                const float zz = proj[2][srow][scol];
                const float c_ = creg*fgv + zz - ig;
                creg = c_;
                const float h_ = sigmoidf_(c_) - og;
                const unsigned hu = __float_as_uint(h_);
                const unsigned pu = (unsigned)__builtin_amdgcn_ds_swizzle((int)hu, 0x041F);
                unsigned pay;
                asm volatile("v_cvt_pk_bf16_f32 %0, %1, %2"
                             : "=v"(pay) : "v"(h_), "v"(__uint_as_float(pu)));
                if (!(scol & 1)) {
                    const size_t off = (((size_t)(t & 3)*8 + g)*32 + bidx)*64
                                     + srow*8 + (scol >> 1);
                    ring_st(ring1 + off, (u64)pay | ((u64)(unsigned)(t + 1) << 32));
                }
                pend_t = t; pend_h = h_; pend_c = c_;
            }
            // issues: next vh (h0_{t+1}) + next vb (h1_t)
            if (t + 1 < TSTEPS) {
                const u64* rbF = ring0 + ((size_t)((t + 1) & 7)*8 + g)*2048;
                const u64* rbB = ring1 + ((size_t)(t & 3)*8 + g)*2048;
#pragma unroll
                for (int k = 0; k < 8; ++k) {
                    va[k]     = ring_ld(rbF + tid + (k << 8));
                    va[8 + k] = ring_ld(rbB + tid + (k << 8));
                }
            }
        }
    }

    // ---- post-loop: L1 flush last out + finals ----
    if (!isL0 && pend_t >= 0) {
        out[((size_t)pend_t*BATCH + g*GROWS + srow)*HID + col0 + scol] = pend_h;
        if (pend_t == TSTEPS - 1) {
            const size_t fo = (size_t)TSTEPS*BATCH*HID
                            + ((size_t)BATCH + g*GROWS + srow)*HID + col0 + scol;
            out[fo] = pend_h;
            out[fo + (size_t)2*BATCH*HID] = pend_c;
        }
    }
}

extern "C" void kernel_launch(void* const* d_in, const int* in_sizes, int n_in,
                              void* d_out, int out_size, void* d_ws, size_t ws_size,
                              hipStream_t stream)
{
    (void)in_sizes; (void)n_in; (void)out_size; (void)ws_size;
    const float* x  = (const float*)d_in[0];
    const float* h0 = (const float*)d_in[1];
    const float* c0 = (const float*)d_in[2];
    const float* W  = (const float*)d_in[3];
    const float* R  = (const float*)d_in[4];
    const float* bi = (const float*)d_in[5];
    const float* bh = (const float*)d_in[6];
    const float* fw = (const float*)d_in[7];
    float* out = (float*)d_out;

    u64* ring0 = (u64*)d_ws;                                            // 1 MB (8 slots)
    u64* ring1 = (u64*)((char*)d_ws + (1u << 20));                      // 512 KB (4 slots)
    unsigned* prog = (unsigned*)((char*)d_ws + 0x180000);               // 4 KB
    unsigned short* xbuf = (unsigned short*)((char*)d_ws + (2u << 20)); // 64 MB

    hipMemsetAsync(d_ws, 0, 2u << 20, stream);   // rings + prog (replay-safe)

    xconvert<<<dim3(TSTEPS*BATCH*HID/(256*8)), dim3(256), 0, stream>>>(x, xbuf);

    sublstm_split<<<dim3(512), dim3(NT), 0, stream>>>(
        xbuf, W, R, bi, bh, fw, h0, c0, ring0, ring1, prog, out);
}